// Round 4
// baseline (329.017 us; speedup 1.0000x reference)
//
#include <hip/hip_runtime.h>
#include <hip/hip_bf16.h>
#include <hip/hip_fp16.h>

#define NN 50000
#define INCH 512
#define OUTCH 64
#define NB 196            // ceil(50000/256)
#define NTILES 3125       // 50000 / 16 (exact)

typedef __attribute__((ext_vector_type(8))) short short8;
typedef __attribute__((ext_vector_type(4))) float floatx4;

__device__ __forceinline__ unsigned short f2bf(float f) {
    unsigned u = __float_as_uint(f);
    return (unsigned short)((u + 0x7FFFu + ((u >> 16) & 1u)) >> 16);  // RNE
}

// ---------------- histogram of destination rows ----------------
__global__ void hist_kernel(const int* __restrict__ rows, int* __restrict__ deg, int n) {
    int e = blockIdx.x * blockDim.x + threadIdx.x;
    if (e < n) atomicAdd(&deg[rows[e]], 1);
}

// ---------------- hierarchical scan: block partial sums ----------------
__global__ __launch_bounds__(256) void partial_kernel(const int* __restrict__ deg,
                                                      int* __restrict__ bsum, int n) {
    int i = blockIdx.x * 256 + threadIdx.x;
    int v = (i < n) ? deg[i] : 0;
#pragma unroll
    for (int o = 32; o > 0; o >>= 1) v += __shfl_down(v, o, 64);
    __shared__ int ws[4];
    if ((threadIdx.x & 63) == 0) ws[threadIdx.x >> 6] = v;
    __syncthreads();
    if (threadIdx.x == 0) bsum[blockIdx.x] = ws[0] + ws[1] + ws[2] + ws[3];
}

// ---------------- scan the 196 partials (1 block) ----------------
__global__ __launch_bounds__(256) void scanpart_kernel(const int* __restrict__ bsum,
                                                       int* __restrict__ bpre,
                                                       int* __restrict__ offs, int Etot) {
    __shared__ int sd[256];
    const int t = threadIdx.x;
    int v = (t < NB) ? bsum[t] : 0;
    sd[t] = v;
    __syncthreads();
#pragma unroll
    for (int o = 1; o < 256; o <<= 1) {
        int y = (t >= o) ? sd[t - o] : 0;
        __syncthreads();
        sd[t] += y;
        __syncthreads();
    }
    if (t < NB) bpre[t] = sd[t] - v;     // exclusive
    if (t == 0) offs[NN] = Etot;
}

// ---------------- per-block rescan + add block prefix ----------------
__global__ __launch_bounds__(256) void scanfinal_kernel(const int* __restrict__ deg,
                                                        const int* __restrict__ bpre,
                                                        int* __restrict__ offs,
                                                        int* __restrict__ cursor, int n) {
    __shared__ int sd[256];
    const int t = threadIdx.x;
    const int i = blockIdx.x * 256 + t;
    int v = (i < n) ? deg[i] : 0;
    sd[t] = v;
    __syncthreads();
#pragma unroll
    for (int o = 1; o < 256; o <<= 1) {
        int y = (t >= o) ? sd[t - o] : 0;
        __syncthreads();
        sd[t] += y;
        __syncthreads();
    }
    if (i < n) {
        int ex = bpre[blockIdx.x] + sd[t] - v;
        offs[i] = ex;
        cursor[i] = ex;
    }
}

// ---------------- scatter edges into row-sorted packed array ----------------
// packed edge: low 16 bits = col (N < 65536), high 16 bits = value as fp16
__global__ void scatter_kernel(const int* __restrict__ rows, const int* __restrict__ cols,
                               const float* __restrict__ vals, int* __restrict__ cursor,
                               unsigned* __restrict__ edges, int n) {
    int e = blockIdx.x * blockDim.x + threadIdx.x;
    if (e >= n) return;
    int r = rows[e];
    int p = atomicAdd(&cursor[r], 1);
    unsigned short hv = __half_as_ushort(__float2half(vals[e]));
    edges[p] = (unsigned)cols[e] | ((unsigned)hv << 16);
}

// ---------------- dense projection: x0 = features @ W via bf16 MFMA ----------------
// W staged ONCE to LDS ([n][k] bf16, stride 520 -> conflict-free b128 reads),
// then a barrier-free K-loop: each wave owns 16 rows, A-frags straight from global.
#define WSTR 520
__global__ __launch_bounds__(256) void gemm_mfma(const float* __restrict__ A,
                                                 const float* __restrict__ B,
                                                 float* __restrict__ C) {
    __shared__ unsigned short Ws[64 * WSTR];   // 66560 B -> 2 blocks/CU
    const int t = threadIdx.x;
    const int lane = t & 63;
    const int wave = t >> 6;

    // ---- stage W: [k][n] fp32 global -> [n][k] bf16 LDS ----
    {
        const int kb = t >> 4;          // 0..15
        const int n4 = (t & 15) * 4;    // 0..60
#pragma unroll
        for (int c = 0; c < 32; ++c) {
            const int k = kb + c * 16;
            const float4 w = *(const float4*)(B + k * OUTCH + n4);
            Ws[(n4 + 0) * WSTR + k] = f2bf(w.x);
            Ws[(n4 + 1) * WSTR + k] = f2bf(w.y);
            Ws[(n4 + 2) * WSTR + k] = f2bf(w.z);
            Ws[(n4 + 3) * WSTR + k] = f2bf(w.w);
        }
    }
    __syncthreads();

    const int tile = blockIdx.x * 4 + wave;
    if (tile >= NTILES) return;
    const int rbase = tile * 16;
    const int frow = lane & 15;
    const int quad = lane >> 4;
    const float* Ap = A + (size_t)(rbase + frow) * INCH + quad * 8;

    floatx4 acc[4] = {floatx4{0,0,0,0}, floatx4{0,0,0,0}, floatx4{0,0,0,0}, floatx4{0,0,0,0}};

    float4 a0 = *(const float4*)(Ap);
    float4 a1 = *(const float4*)(Ap + 4);
    for (int c = 0; c < 16; ++c) {
        const float4 c0 = a0, c1 = a1;
        if (c < 15) {
            const float* An = Ap + (c + 1) * 32;
            a0 = *(const float4*)(An);
            a1 = *(const float4*)(An + 4);
        }
        short8 af;
        af[0] = (short)f2bf(c0.x); af[1] = (short)f2bf(c0.y);
        af[2] = (short)f2bf(c0.z); af[3] = (short)f2bf(c0.w);
        af[4] = (short)f2bf(c1.x); af[5] = (short)f2bf(c1.y);
        af[6] = (short)f2bf(c1.z); af[7] = (short)f2bf(c1.w);
        const int koff = c * 32 + quad * 8;
#pragma unroll
        for (int f = 0; f < 4; ++f) {
            const short8 bfr = *(const short8*)&Ws[(f * 16 + frow) * WSTR + koff];
            acc[f] = __builtin_amdgcn_mfma_f32_16x16x32_bf16(af, bfr, acc[f], 0, 0, 0);
        }
    }

    // C/D layout: col = lane&15 (n), row = quad*4 + reg   [m89]
#pragma unroll
    for (int f = 0; f < 4; ++f) {
#pragma unroll
        for (int reg = 0; reg < 4; ++reg) {
            C[(size_t)(rbase + quad * 4 + reg) * OUTCH + f * 16 + frow] = acc[f][reg];
        }
    }
}

// ---------------- SpMM gather: ONE wave per row, 4 edge-slots x 16 channel-lanes ----
// No cross-row divergence inside a wave; 4 independent gather chains; shuffle-reduce.
__global__ __launch_bounds__(256) void spmm_kernel(const int* __restrict__ offs,
                                                   const unsigned* __restrict__ edges,
                                                   const float* __restrict__ xin,
                                                   float* __restrict__ xout,
                                                   const float* __restrict__ bias) {
    const int t = threadIdx.x;
    const int lane = t & 63;
    const int eslot = lane >> 4;        // 0..3: edge slot
    const int c4 = (lane & 15) * 4;     // channel base
    const int row = blockIdx.x * 4 + (t >> 6);   // NN = 4 * 12500 exact
    const int s = offs[row];
    const int e = offs[row + 1];
    float4 acc = make_float4(0.f, 0.f, 0.f, 0.f);
    for (int i = s + eslot; i < e; i += 4) {
        const unsigned p = edges[i];
        const float4 x = *(const float4*)(xin + (size_t)(p & 0xFFFFu) * OUTCH + c4);
        const float v = __half2float(__ushort_as_half((unsigned short)(p >> 16)));
        acc.x = fmaf(v, x.x, acc.x); acc.y = fmaf(v, x.y, acc.y);
        acc.z = fmaf(v, x.z, acc.z); acc.w = fmaf(v, x.w, acc.w);
    }
    // reduce the 4 edge-slots (lane bits 4,5)
    acc.x += __shfl_xor(acc.x, 16, 64); acc.y += __shfl_xor(acc.y, 16, 64);
    acc.z += __shfl_xor(acc.z, 16, 64); acc.w += __shfl_xor(acc.w, 16, 64);
    acc.x += __shfl_xor(acc.x, 32, 64); acc.y += __shfl_xor(acc.y, 32, 64);
    acc.z += __shfl_xor(acc.z, 32, 64); acc.w += __shfl_xor(acc.w, 32, 64);
    if (eslot == 0) {
        if (bias) {
            const float4 bv = *(const float4*)(bias + c4);
            acc.x += bv.x; acc.y += bv.y; acc.z += bv.z; acc.w += bv.w;
        }
        *(float4*)(xout + (size_t)row * OUTCH + c4) = acc;
    }
}

extern "C" void kernel_launch(void* const* d_in, const int* in_sizes, int n_in,
                              void* d_out, int out_size, void* d_ws, size_t ws_size,
                              hipStream_t stream) {
    const int*   adj   = (const int*)d_in[0];     // [2, E]
    const float* avals = (const float*)d_in[1];   // [E]
    const float* feat  = (const float*)d_in[2];   // [N, 512]
    const float* W     = (const float*)d_in[3];   // [512, 64]
    const float* bias  = (const float*)d_in[4];   // [64]
    float* out = (float*)d_out;

    const int E_ = in_sizes[1];
    const int* rows = adj;
    const int* cols = adj + E_;

    // workspace layout (16B-aligned segments)
    float*    x0     = (float*)d_ws;                      // N*64 floats (12.8 MB)
    float*    x1     = x0 + (size_t)NN * OUTCH;           // N*64 floats (12.8 MB)
    unsigned* edges  = (unsigned*)(x1 + (size_t)NN * OUTCH);  // E u32 (3.2 MB)
    int*      deg    = (int*)(edges + E_);                // N
    int*      offs   = deg + NN;                          // N+1
    int*      cursor = offs + NN + 1;                     // N
    int*      bsum   = cursor + NN;                       // NB
    int*      bpre   = bsum + NB;                         // NB

    // ---- CSR build ----
    hipMemsetAsync(deg, 0, NN * sizeof(int), stream);
    hist_kernel<<<(E_ + 255) / 256, 256, 0, stream>>>(rows, deg, E_);
    partial_kernel<<<NB, 256, 0, stream>>>(deg, bsum, NN);
    scanpart_kernel<<<1, 256, 0, stream>>>(bsum, bpre, offs, E_);
    scanfinal_kernel<<<NB, 256, 0, stream>>>(deg, bpre, offs, cursor, NN);
    scatter_kernel<<<(E_ + 255) / 256, 256, 0, stream>>>(rows, cols, avals, cursor, edges, E_);

    // ---- dense projection (bf16 MFMA, barrier-free K-loop) ----
    gemm_mfma<<<(NTILES + 3) / 4, 256, 0, stream>>>(feat, W, x0);

    // ---- two SpMM hops; bias fused into the last ----
    spmm_kernel<<<NN / 4, 256, 0, stream>>>(offs, edges, x0, x1, nullptr);
    spmm_kernel<<<NN / 4, 256, 0, stream>>>(offs, edges, x1, out, bias);
}

// Round 5
// 284.739 us; speedup vs baseline: 1.1555x; 1.1555x over previous
//
#include <hip/hip_runtime.h>
#include <hip/hip_bf16.h>
#include <hip/hip_fp16.h>

#define NN 50000
#define INCH 512
#define OUTCH 64
#define NTILES 3125       // 50000 / 16 (exact)
#define MAXD 96           // ELL slots per row; Poisson(16) tail at 96 is ~1e-30

typedef __attribute__((ext_vector_type(8))) short short8;
typedef __attribute__((ext_vector_type(4))) float floatx4;

__device__ __forceinline__ unsigned packbf2(float a, float b) {
    __hip_bfloat162 h = __float22bfloat162_rn(make_float2(a, b));  // v_cvt_pk_bf16_f32 RNE
    unsigned r;
    __builtin_memcpy(&r, &h, 4);
    return r;
}
__device__ __forceinline__ unsigned short f2bf(float f) {
    unsigned u = __float_as_uint(f);
    return (unsigned short)((u + 0x7FFFu + ((u >> 16) & 1u)) >> 16);  // RNE
}

// ---------------- fused hist + scatter into ELL ----------------
// packed edge: low 16 bits = col (N < 65536), high 16 bits = value as fp16
__global__ void scatter_ell(const int* __restrict__ rows, const int* __restrict__ cols,
                            const float* __restrict__ vals, int* __restrict__ deg,
                            unsigned* __restrict__ ell, int n) {
    int e = blockIdx.x * blockDim.x + threadIdx.x;
    if (e >= n) return;
    int r = rows[e];
    int slot = atomicAdd(&deg[r], 1);
    unsigned short hv = __half_as_ushort(__float2half(vals[e]));
    if (slot < MAXD) ell[(size_t)r * MAXD + slot] = (unsigned)cols[e] | ((unsigned)hv << 16);
}

// ---------------- dense projection: x0 = features @ W via bf16 MFMA ----------------
// W staged ONCE to LDS ([n][k] bf16, stride 520 -> conflict-free b128 reads),
// then a barrier-free K-loop: each wave owns 16 rows, A-frags straight from global.
#define WSTR 520
__global__ __launch_bounds__(256) void gemm_mfma(const float* __restrict__ A,
                                                 const float* __restrict__ B,
                                                 float* __restrict__ C) {
    __shared__ unsigned short Ws[64 * WSTR];   // 66560 B -> 2 blocks/CU
    const int t = threadIdx.x;
    const int lane = t & 63;
    const int wave = t >> 6;

    // ---- stage W: [k][n] fp32 global -> [n][k] bf16 LDS, paired k for b32 writes ----
    {
        const int k2 = (t >> 4) * 2;    // 0,2,..,30
        const int n4 = (t & 15) * 4;    // 0..60
#pragma unroll
        for (int c = 0; c < 16; ++c) {
            const int k = k2 + c * 32;
            const float4 w0 = *(const float4*)(B + (k + 0) * OUTCH + n4);
            const float4 w1 = *(const float4*)(B + (k + 1) * OUTCH + n4);
            *(unsigned*)&Ws[(n4 + 0) * WSTR + k] = packbf2(w0.x, w1.x);
            *(unsigned*)&Ws[(n4 + 1) * WSTR + k] = packbf2(w0.y, w1.y);
            *(unsigned*)&Ws[(n4 + 2) * WSTR + k] = packbf2(w0.z, w1.z);
            *(unsigned*)&Ws[(n4 + 3) * WSTR + k] = packbf2(w0.w, w1.w);
        }
    }
    __syncthreads();

    const int tile = blockIdx.x * 4 + wave;
    if (tile >= NTILES) return;
    const int rbase = tile * 16;
    const int frow = lane & 15;
    const int quad = lane >> 4;
    const float* Ap = A + (size_t)(rbase + frow) * INCH + quad * 8;

    floatx4 acc[4] = {floatx4{0,0,0,0}, floatx4{0,0,0,0}, floatx4{0,0,0,0}, floatx4{0,0,0,0}};

    float4 a0 = *(const float4*)(Ap);
    float4 a1 = *(const float4*)(Ap + 4);
    for (int c = 0; c < 16; ++c) {
        const float4 c0 = a0, c1 = a1;
        if (c < 15) {
            const float* An = Ap + (c + 1) * 32;
            a0 = *(const float4*)(An);
            a1 = *(const float4*)(An + 4);
        }
        uint4 au;
        au.x = packbf2(c0.x, c0.y);
        au.y = packbf2(c0.z, c0.w);
        au.z = packbf2(c1.x, c1.y);
        au.w = packbf2(c1.z, c1.w);
        const short8 af = *(const short8*)&au;
        const int koff = c * 32 + quad * 8;
#pragma unroll
        for (int f = 0; f < 4; ++f) {
            const short8 bfr = *(const short8*)&Ws[(f * 16 + frow) * WSTR + koff];
            acc[f] = __builtin_amdgcn_mfma_f32_16x16x32_bf16(af, bfr, acc[f], 0, 0, 0);
        }
    }

    // C/D layout: col = lane&15 (n), row = quad*4 + reg   [m89]
#pragma unroll
    for (int f = 0; f < 4; ++f) {
#pragma unroll
        for (int reg = 0; reg < 4; ++reg) {
            C[(size_t)(rbase + quad * 4 + reg) * OUTCH + f * 16 + frow] = acc[f][reg];
        }
    }
}

// ---------------- SpMM gather over ELL: one wave per row, 4 edge-slots x 16 lanes ----
__global__ __launch_bounds__(256) void spmm_ell(const int* __restrict__ deg,
                                                const unsigned* __restrict__ ell,
                                                const float* __restrict__ xin,
                                                float* __restrict__ xout,
                                                const float* __restrict__ bias) {
    const int t = threadIdx.x;
    const int lane = t & 63;
    const int eslot = lane >> 4;        // 0..3: edge slot
    const int c4 = (lane & 15) * 4;     // channel base
    const int row = blockIdx.x * 4 + (t >> 6);   // NN = 4 * 12500 exact
    const int d = deg[row];
    const unsigned* ebase = ell + (size_t)row * MAXD;
    float4 acc = make_float4(0.f, 0.f, 0.f, 0.f);
    for (int i = eslot; i < d; i += 4) {
        const unsigned p = ebase[i];
        const float4 x = *(const float4*)(xin + (size_t)(p & 0xFFFFu) * OUTCH + c4);
        const float v = __half2float(__ushort_as_half((unsigned short)(p >> 16)));
        acc.x = fmaf(v, x.x, acc.x); acc.y = fmaf(v, x.y, acc.y);
        acc.z = fmaf(v, x.z, acc.z); acc.w = fmaf(v, x.w, acc.w);
    }
    // reduce the 4 edge-slots (lane bits 4,5)
    acc.x += __shfl_xor(acc.x, 16, 64); acc.y += __shfl_xor(acc.y, 16, 64);
    acc.z += __shfl_xor(acc.z, 16, 64); acc.w += __shfl_xor(acc.w, 16, 64);
    acc.x += __shfl_xor(acc.x, 32, 64); acc.y += __shfl_xor(acc.y, 32, 64);
    acc.z += __shfl_xor(acc.z, 32, 64); acc.w += __shfl_xor(acc.w, 32, 64);
    if (eslot == 0) {
        if (bias) {
            const float4 bv = *(const float4*)(bias + c4);
            acc.x += bv.x; acc.y += bv.y; acc.z += bv.z; acc.w += bv.w;
        }
        *(float4*)(xout + (size_t)row * OUTCH + c4) = acc;
    }
}

extern "C" void kernel_launch(void* const* d_in, const int* in_sizes, int n_in,
                              void* d_out, int out_size, void* d_ws, size_t ws_size,
                              hipStream_t stream) {
    const int*   adj   = (const int*)d_in[0];     // [2, E]
    const float* avals = (const float*)d_in[1];   // [E]
    const float* feat  = (const float*)d_in[2];   // [N, 512]
    const float* W     = (const float*)d_in[3];   // [512, 64]
    const float* bias  = (const float*)d_in[4];   // [64]
    float* out = (float*)d_out;

    const int E_ = in_sizes[1];
    const int* rows = adj;
    const int* cols = adj + E_;

    // workspace layout (16B-aligned segments)
    float*    x0   = (float*)d_ws;                         // N*64 floats (12.8 MB)
    float*    x1   = x0 + (size_t)NN * OUTCH;              // N*64 floats (12.8 MB)
    unsigned* ell  = (unsigned*)(x1 + (size_t)NN * OUTCH); // N*MAXD u32 (19.2 MB)
    int*      deg  = (int*)(ell + (size_t)NN * MAXD);      // N

    // ---- ELL build (no scan needed) ----
    hipMemsetAsync(deg, 0, NN * sizeof(int), stream);
    scatter_ell<<<(E_ + 255) / 256, 256, 0, stream>>>(rows, cols, avals, deg, ell, E_);

    // ---- dense projection (bf16 MFMA, barrier-free K-loop) ----
    gemm_mfma<<<(NTILES + 3) / 4, 256, 0, stream>>>(feat, W, x0);

    // ---- two SpMM hops; bias fused into the last ----
    spmm_ell<<<NN / 4, 256, 0, stream>>>(deg, ell, x0, x1, nullptr);
    spmm_ell<<<NN / 4, 256, 0, stream>>>(deg, ell, x1, out, bias);
}

// Round 6
// 271.306 us; speedup vs baseline: 1.2127x; 1.0495x over previous
//
#include <hip/hip_runtime.h>
#include <hip/hip_bf16.h>
#include <hip/hip_fp16.h>

#define NN 50000
#define INCH 512
#define OUTCH 64
#define NTILES 3125       // 50000 / 16 (exact)
#define MAXD 96           // ELL slots per row; Poisson(16) tail at 96 is ~1e-30
#define GB 782            // gemm blocks: ceil(3125 tiles / 4 waves)
#define SB 256            // scatter blocks appended after gemm blocks

typedef __attribute__((ext_vector_type(8))) short short8;
typedef __attribute__((ext_vector_type(4))) float floatx4;

__device__ __forceinline__ unsigned packbf2(float a, float b) {
    __hip_bfloat162 h = __float22bfloat162_rn(make_float2(a, b));  // v_cvt_pk_bf16_f32 RNE
    unsigned r;
    __builtin_memcpy(&r, &h, 4);
    return r;
}
__device__ __forceinline__ unsigned short f2bf(float f) {
    unsigned u = __float_as_uint(f);
    return (unsigned short)((u + 0x7FFFu + ((u >> 16) & 1u)) >> 16);  // RNE
}
__device__ __forceinline__ float bf2f(unsigned short u) {
    return __uint_as_float(((unsigned)u) << 16);
}

// ---------------- fused: [blocks 0..GB) gemm | [GB..GB+SB) ELL scatter ----------------
// gemm: W staged ONCE to LDS ([n][k] bf16, stride 520, conflict-free b128 reads),
// barrier-free K-loop, each wave owns 16 rows; epilogue stores x0 as bf16.
// scatter: grid-stride over E; packed edge = col | (fp16(val) << 16).
#define WSTR 520
__global__ __launch_bounds__(256) void fused_gemm_scatter(
        const float* __restrict__ A, const float* __restrict__ B,
        unsigned short* __restrict__ C,
        const int* __restrict__ rows, const int* __restrict__ cols,
        const float* __restrict__ vals, int* __restrict__ deg,
        unsigned* __restrict__ ell, int E_) {
    __shared__ unsigned short Ws[64 * WSTR];   // 66560 B -> 2 blocks/CU
    const int t = threadIdx.x;

    if (blockIdx.x >= GB) {
        // ---------- scatter part ----------
        for (int e = (blockIdx.x - GB) * 256 + t; e < E_; e += SB * 256) {
            const int r = rows[e];
            const int slot = atomicAdd(&deg[r], 1);
            const unsigned short hv = __half_as_ushort(__float2half(vals[e]));
            if (slot < MAXD)
                ell[(size_t)r * MAXD + slot] = (unsigned)cols[e] | ((unsigned)hv << 16);
        }
        return;
    }

    // ---------- gemm part ----------
    const int lane = t & 63;
    const int wave = t >> 6;

    // stage W: [k][n] fp32 global -> [n][k] bf16 LDS, paired k for b32 writes
    {
        const int k2 = (t >> 4) * 2;    // 0,2,..,30
        const int n4 = (t & 15) * 4;    // 0..60
#pragma unroll
        for (int c = 0; c < 16; ++c) {
            const int k = k2 + c * 32;
            const float4 w0 = *(const float4*)(B + (k + 0) * OUTCH + n4);
            const float4 w1 = *(const float4*)(B + (k + 1) * OUTCH + n4);
            *(unsigned*)&Ws[(n4 + 0) * WSTR + k] = packbf2(w0.x, w1.x);
            *(unsigned*)&Ws[(n4 + 1) * WSTR + k] = packbf2(w0.y, w1.y);
            *(unsigned*)&Ws[(n4 + 2) * WSTR + k] = packbf2(w0.z, w1.z);
            *(unsigned*)&Ws[(n4 + 3) * WSTR + k] = packbf2(w0.w, w1.w);
        }
    }
    __syncthreads();

    const int tile = blockIdx.x * 4 + wave;
    if (tile >= NTILES) return;
    const int rbase = tile * 16;
    const int frow = lane & 15;
    const int quad = lane >> 4;
    const float* Ap = A + (size_t)(rbase + frow) * INCH + quad * 8;

    floatx4 acc[4] = {floatx4{0,0,0,0}, floatx4{0,0,0,0}, floatx4{0,0,0,0}, floatx4{0,0,0,0}};

    float4 a0 = *(const float4*)(Ap);
    float4 a1 = *(const float4*)(Ap + 4);
    for (int c = 0; c < 16; ++c) {
        const float4 c0 = a0, c1 = a1;
        if (c < 15) {
            const float* An = Ap + (c + 1) * 32;
            a0 = *(const float4*)(An);
            a1 = *(const float4*)(An + 4);
        }
        uint4 au;
        au.x = packbf2(c0.x, c0.y);
        au.y = packbf2(c0.z, c0.w);
        au.z = packbf2(c1.x, c1.y);
        au.w = packbf2(c1.z, c1.w);
        const short8 af = *(const short8*)&au;
        const int koff = c * 32 + quad * 8;
#pragma unroll
        for (int f = 0; f < 4; ++f) {
            const short8 bfr = *(const short8*)&Ws[(f * 16 + frow) * WSTR + koff];
            acc[f] = __builtin_amdgcn_mfma_f32_16x16x32_bf16(af, bfr, acc[f], 0, 0, 0);
        }
    }

    // C/D layout: col = lane&15 (n), row = quad*4 + reg   [m89]; store bf16
#pragma unroll
    for (int f = 0; f < 4; ++f) {
#pragma unroll
        for (int reg = 0; reg < 4; ++reg) {
            C[(size_t)(rbase + quad * 4 + reg) * OUTCH + f * 16 + frow] = f2bf(acc[f][reg]);
        }
    }
}

// ---------------- SpMM over ELL: one wave per row, 4 edge-slots x 16 lanes ----------
// xin is bf16 [N,64]; LAST=false -> write bf16, LAST=true -> +bias, write fp32.
template <bool LAST>
__global__ __launch_bounds__(256) void spmm_ell(const int* __restrict__ deg,
                                                const unsigned* __restrict__ ell,
                                                const unsigned short* __restrict__ xin,
                                                void* __restrict__ xout_,
                                                const float* __restrict__ bias) {
    const int t = threadIdx.x;
    const int lane = t & 63;
    const int eslot = lane >> 4;        // 0..3: edge slot
    const int c4 = (lane & 15) * 4;     // channel base
    const int row = blockIdx.x * 4 + (t >> 6);   // NN = 4 * 12500 exact
    const int d = deg[row];
    const unsigned* ebase = ell + (size_t)row * MAXD;
    float4 acc = make_float4(0.f, 0.f, 0.f, 0.f);
    for (int i = eslot; i < d; i += 4) {
        const unsigned p = ebase[i];
        const ushort4 xv = *(const ushort4*)(xin + (size_t)(p & 0xFFFFu) * OUTCH + c4);
        const float v = __half2float(__ushort_as_half((unsigned short)(p >> 16)));
        acc.x = fmaf(v, bf2f(xv.x), acc.x);
        acc.y = fmaf(v, bf2f(xv.y), acc.y);
        acc.z = fmaf(v, bf2f(xv.z), acc.z);
        acc.w = fmaf(v, bf2f(xv.w), acc.w);
    }
    // reduce the 4 edge-slots (lane bits 4,5)
    acc.x += __shfl_xor(acc.x, 16, 64); acc.y += __shfl_xor(acc.y, 16, 64);
    acc.z += __shfl_xor(acc.z, 16, 64); acc.w += __shfl_xor(acc.w, 16, 64);
    acc.x += __shfl_xor(acc.x, 32, 64); acc.y += __shfl_xor(acc.y, 32, 64);
    acc.z += __shfl_xor(acc.z, 32, 64); acc.w += __shfl_xor(acc.w, 32, 64);
    if (eslot == 0) {
        if (LAST) {
            const float4 bv = *(const float4*)(bias + c4);
            acc.x += bv.x; acc.y += bv.y; acc.z += bv.z; acc.w += bv.w;
            *(float4*)((float*)xout_ + (size_t)row * OUTCH + c4) = acc;
        } else {
            ushort4 o;
            o.x = f2bf(acc.x); o.y = f2bf(acc.y); o.z = f2bf(acc.z); o.w = f2bf(acc.w);
            *(ushort4*)((unsigned short*)xout_ + (size_t)row * OUTCH + c4) = o;
        }
    }
}

extern "C" void kernel_launch(void* const* d_in, const int* in_sizes, int n_in,
                              void* d_out, int out_size, void* d_ws, size_t ws_size,
                              hipStream_t stream) {
    const int*   adj   = (const int*)d_in[0];     // [2, E]
    const float* avals = (const float*)d_in[1];   // [E]
    const float* feat  = (const float*)d_in[2];   // [N, 512]
    const float* W     = (const float*)d_in[3];   // [512, 64]
    const float* bias  = (const float*)d_in[4];   // [64]
    float* out = (float*)d_out;

    const int E_ = in_sizes[1];
    const int* rows = adj;
    const int* cols = adj + E_;

    // workspace layout (16B-aligned segments)
    unsigned short* x0 = (unsigned short*)d_ws;            // N*64 bf16 (6.4 MB)
    unsigned short* x1 = x0 + (size_t)NN * OUTCH;          // N*64 bf16 (6.4 MB)
    unsigned* ell = (unsigned*)(x1 + (size_t)NN * OUTCH);  // N*MAXD u32 (19.2 MB)
    int* deg = (int*)(ell + (size_t)NN * MAXD);            // N

    // ---- zero degree counters ----
    hipMemsetAsync(deg, 0, NN * sizeof(int), stream);

    // ---- fused: dense projection (bf16 MFMA) + ELL scatter ----
    fused_gemm_scatter<<<GB + SB, 256, 0, stream>>>(feat, W, x0, rows, cols, avals,
                                                    deg, ell, E_);

    // ---- two SpMM hops; bias fused into the last ----
    spmm_ell<false><<<NN / 4, 256, 0, stream>>>(deg, ell, x0, x1, nullptr);
    spmm_ell<true><<<NN / 4, 256, 0, stream>>>(deg, ell, x1, out, bias);
}

// Round 7
// 260.679 us; speedup vs baseline: 1.2622x; 1.0408x over previous
//
#include <hip/hip_runtime.h>
#include <hip/hip_bf16.h>
#include <hip/hip_fp16.h>

#define NN 50000
#define INCH 512
#define OUTCH 64
#define NTILES 3125       // 50000 / 16 (exact)
#define MAXD 96           // ELL slots per row; Poisson(16) tail at 96 is ~1e-30
#define GB 782            // gemm blocks: ceil(3125 tiles / 4 waves)
#define SB 256            // scatter blocks appended after gemm blocks

typedef __attribute__((ext_vector_type(8))) short short8;
typedef __attribute__((ext_vector_type(4))) float floatx4;

__device__ __forceinline__ unsigned packbf2(float a, float b) {
    __hip_bfloat162 h = __float22bfloat162_rn(make_float2(a, b));  // v_cvt_pk_bf16_f32 RNE
    unsigned r;
    __builtin_memcpy(&r, &h, 4);
    return r;
}
__device__ __forceinline__ unsigned short f2bf(float f) {
    unsigned u = __float_as_uint(f);
    return (unsigned short)((u + 0x7FFFu + ((u >> 16) & 1u)) >> 16);  // RNE
}
__device__ __forceinline__ float bf2f(unsigned short u) {
    return __uint_as_float(((unsigned)u) << 16);
}

// ---------------- prep: zero deg + convert W fp32 [k][n] -> bf16 [n][k] global ----------
__global__ __launch_bounds__(256) void prep_kernel(const float* __restrict__ W,
                                                   unsigned short* __restrict__ Wbf,
                                                   int* __restrict__ deg) {
    const int i = blockIdx.x * 256 + threadIdx.x;
    if (i < NN) deg[i] = 0;
    if (i < INCH * OUTCH) {
        const int k = i >> 6;          // W is [k][n], read coalesced
        const int n = i & 63;
        Wbf[n * INCH + k] = f2bf(W[i]);
    }
}

// ---------------- fused: [blocks 0..GB) gemm | [GB..GB+SB) ELL scatter ----------------
// gemm: NO W-LDS — B-fragments read from L2-resident global Wbf ([n][k] bf16).
// Barrier-free, fully-unrolled K-loop; each wave owns 16 rows.
// Epilogue: per-wave LDS transpose -> coalesced 1-KB dwordx4 bf16 stores.
__global__ __launch_bounds__(256, 4) void fused_gemm_scatter(
        const float* __restrict__ A, const unsigned short* __restrict__ Wbf,
        unsigned short* __restrict__ C,
        const int* __restrict__ rows, const int* __restrict__ cols,
        const float* __restrict__ vals, int* __restrict__ deg,
        unsigned* __restrict__ ell, int E_) {
    __shared__ unsigned short ldsT[4][16 * 64];   // 2 KB per wave, 8 KB total
    const int t = threadIdx.x;

    if (blockIdx.x >= GB) {
        // ---------- scatter part ----------
        for (int e = (blockIdx.x - GB) * 256 + t; e < E_; e += SB * 256) {
            const int r = rows[e];
            const int slot = atomicAdd(&deg[r], 1);
            const unsigned short hv = __half_as_ushort(__float2half(vals[e]));
            if (slot < MAXD)
                ell[(size_t)r * MAXD + slot] = (unsigned)cols[e] | ((unsigned)hv << 16);
        }
        return;
    }

    // ---------- gemm part ----------
    const int lane = t & 63;
    const int wave = t >> 6;
    const int tile = blockIdx.x * 4 + wave;
    if (tile >= NTILES) return;
    const int rbase = tile * 16;
    const int frow = lane & 15;
    const int quad = lane >> 4;
    const float* Ap = A + (size_t)(rbase + frow) * INCH + quad * 8;
    const unsigned short* Bp = Wbf + frow * INCH + quad * 8;

    floatx4 acc[4] = {floatx4{0,0,0,0}, floatx4{0,0,0,0}, floatx4{0,0,0,0}, floatx4{0,0,0,0}};

#pragma unroll
    for (int c = 0; c < 16; ++c) {
        const float4 a0 = *(const float4*)(Ap + c * 32);
        const float4 a1 = *(const float4*)(Ap + c * 32 + 4);
        short8 bfr[4];
#pragma unroll
        for (int f = 0; f < 4; ++f)
            bfr[f] = *(const short8*)(Bp + (size_t)f * 16 * INCH + c * 32);
        uint4 au;
        au.x = packbf2(a0.x, a0.y);
        au.y = packbf2(a0.z, a0.w);
        au.z = packbf2(a1.x, a1.y);
        au.w = packbf2(a1.z, a1.w);
        const short8 af = *(const short8*)&au;
#pragma unroll
        for (int f = 0; f < 4; ++f)
            acc[f] = __builtin_amdgcn_mfma_f32_16x16x32_bf16(af, bfr[f], acc[f], 0, 0, 0);
    }

    // ---------- epilogue: LDS transpose to get full-line coalesced stores ----------
    // C/D layout: col = f*16 + frow, row = quad*4 + reg   [m89]
    unsigned short* myT = ldsT[wave];
#pragma unroll
    for (int f = 0; f < 4; ++f)
#pragma unroll
        for (int reg = 0; reg < 4; ++reg)
            myT[(quad * 4 + reg) * 64 + f * 16 + frow] = f2bf(acc[f][reg]);
    // wave-local: ds ordering handled by lgkmcnt, no barrier needed
    unsigned short* Cw = C + (size_t)rbase * OUTCH;
#pragma unroll
    for (int it = 0; it < 2; ++it) {
        const short8 v = *(const short8*)&myT[it * 512 + lane * 8];
        *(short8*)(Cw + it * 512 + lane * 8) = v;
    }
}

// ---------------- SpMM over ELL: one wave per row, 4 edge-slots x 16 lanes ----------
// xin is bf16 [N,64]; LAST=false -> write bf16, LAST=true -> +bias, write fp32.
template <bool LAST>
__global__ __launch_bounds__(256) void spmm_ell(const int* __restrict__ deg,
                                                const unsigned* __restrict__ ell,
                                                const unsigned short* __restrict__ xin,
                                                void* __restrict__ xout_,
                                                const float* __restrict__ bias) {
    const int t = threadIdx.x;
    const int lane = t & 63;
    const int eslot = lane >> 4;        // 0..3: edge slot
    const int c4 = (lane & 15) * 4;     // channel base
    const int row = blockIdx.x * 4 + (t >> 6);   // NN = 4 * 12500 exact
    const int d = deg[row];
    const unsigned* ebase = ell + (size_t)row * MAXD;
    float4 acc = make_float4(0.f, 0.f, 0.f, 0.f);
    for (int i = eslot; i < d; i += 4) {
        const unsigned p = ebase[i];
        const ushort4 xv = *(const ushort4*)(xin + (size_t)(p & 0xFFFFu) * OUTCH + c4);
        const float v = __half2float(__ushort_as_half((unsigned short)(p >> 16)));
        acc.x = fmaf(v, bf2f(xv.x), acc.x);
        acc.y = fmaf(v, bf2f(xv.y), acc.y);
        acc.z = fmaf(v, bf2f(xv.z), acc.z);
        acc.w = fmaf(v, bf2f(xv.w), acc.w);
    }
    // reduce the 4 edge-slots (lane bits 4,5)
    acc.x += __shfl_xor(acc.x, 16, 64); acc.y += __shfl_xor(acc.y, 16, 64);
    acc.z += __shfl_xor(acc.z, 16, 64); acc.w += __shfl_xor(acc.w, 16, 64);
    acc.x += __shfl_xor(acc.x, 32, 64); acc.y += __shfl_xor(acc.y, 32, 64);
    acc.z += __shfl_xor(acc.z, 32, 64); acc.w += __shfl_xor(acc.w, 32, 64);
    if (eslot == 0) {
        if (LAST) {
            const float4 bv = *(const float4*)(bias + c4);
            acc.x += bv.x; acc.y += bv.y; acc.z += bv.z; acc.w += bv.w;
            *(float4*)((float*)xout_ + (size_t)row * OUTCH + c4) = acc;
        } else {
            ushort4 o;
            o.x = f2bf(acc.x); o.y = f2bf(acc.y); o.z = f2bf(acc.z); o.w = f2bf(acc.w);
            *(ushort4*)((unsigned short*)xout_ + (size_t)row * OUTCH + c4) = o;
        }
    }
}

extern "C" void kernel_launch(void* const* d_in, const int* in_sizes, int n_in,
                              void* d_out, int out_size, void* d_ws, size_t ws_size,
                              hipStream_t stream) {
    const int*   adj   = (const int*)d_in[0];     // [2, E]
    const float* avals = (const float*)d_in[1];   // [E]
    const float* feat  = (const float*)d_in[2];   // [N, 512]
    const float* W     = (const float*)d_in[3];   // [512, 64]
    const float* bias  = (const float*)d_in[4];   // [64]
    float* out = (float*)d_out;

    const int E_ = in_sizes[1];
    const int* rows = adj;
    const int* cols = adj + E_;

    // workspace layout (16B-aligned segments)
    unsigned short* x0  = (unsigned short*)d_ws;            // N*64 bf16 (6.4 MB)
    unsigned short* x1  = x0 + (size_t)NN * OUTCH;          // N*64 bf16 (6.4 MB)
    unsigned short* Wbf = x1 + (size_t)NN * OUTCH;          // 64*512 bf16 (64 KB)
    unsigned* ell = (unsigned*)(Wbf + (size_t)OUTCH * INCH);// N*MAXD u32 (19.2 MB)
    int* deg = (int*)(ell + (size_t)NN * MAXD);             // N

    // ---- prep: zero deg + convert W to bf16 [n][k] ----
    prep_kernel<<<(NN + 255) / 256, 256, 0, stream>>>(W, Wbf, deg);

    // ---- fused: dense projection (bf16 MFMA) + ELL scatter ----
    fused_gemm_scatter<<<GB + SB, 256, 0, stream>>>(feat, Wbf, x0, rows, cols, avals,
                                                    deg, ell, E_);

    // ---- two SpMM hops; bias fused into the last ----
    spmm_ell<false><<<NN / 4, 256, 0, stream>>>(deg, ell, x0, x1, nullptr);
    spmm_ell<true><<<NN / 4, 256, 0, stream>>>(deg, ell, x1, out, bias);
}